// Round 1
// baseline (336.580 us; speedup 1.0000x reference)
//
#include <hip/hip_runtime.h>

#define NPATH  2048
#define DIM    64
#define NSTEPS 500

// One wave (64 lanes) per path. Lane j owns x[j] and holds rows j of the
// drift (A) and diffusion (C) matrices in registers (64+64 VGPRs).
// Per step: broadcast x through a private LDS row, 128 FMAs in 4 chains,
// coalesced dW load + ys store (256B per wave each).
__global__ __launch_bounds__(256, 2) void sde_euler_kernel(
    const float* __restrict__ x0,
    const float* __restrict__ dW,
    const float* __restrict__ drift,
    const float* __restrict__ drift_bias,
    const float* __restrict__ diffusion,
    const float* __restrict__ diffusion_bias,
    const float* __restrict__ ts,
    float* __restrict__ out)
{
    __shared__ float xs[4][DIM];          // one row per wave in the block
    __shared__ float ts_s[NSTEPS + 1];

    const int wave = threadIdx.x >> 6;
    const int lane = threadIdx.x & 63;
    const int path = (blockIdx.x << 2) + wave;

    // stage ts (501 floats) into LDS
    for (int i = threadIdx.x; i <= NSTEPS; i += 256) ts_s[i] = ts[i];

    // A row j, C row j -> registers (one-time, L2-resident after first blocks)
    float Arow[DIM], Crow[DIM];
#pragma unroll
    for (int k4 = 0; k4 < DIM / 4; ++k4) {
        const float4 a = *(const float4*)(drift + lane * DIM + k4 * 4);
        const float4 c = *(const float4*)(diffusion + lane * DIM + k4 * 4);
        Arow[4 * k4 + 0] = a.x; Arow[4 * k4 + 1] = a.y;
        Arow[4 * k4 + 2] = a.z; Arow[4 * k4 + 3] = a.w;
        Crow[4 * k4 + 0] = c.x; Crow[4 * k4 + 1] = c.y;
        Crow[4 * k4 + 2] = c.z; Crow[4 * k4 + 3] = c.w;
    }
    const float bj = drift_bias[lane];
    const float dj = diffusion_bias[lane];

    float x = x0[path * DIM + lane];

    const float* dWp  = dW  + (size_t)path * NSTEPS * DIM + lane;
    float*       outp = out + (size_t)path * (NSTEPS + 1) * DIM + lane;
    outp[0] = x;                           // saved initial state

    __syncthreads();                       // ts_s ready

    float dw = dWp[0];
    float t0 = ts_s[0];
    float t1 = ts_s[1];

    for (int s = 0; s < NSTEPS; ++s) {
        // prefetch next step's inputs; consumed at the end of this iteration
        float dw_next = 0.0f;
        float t2 = t1;
        if (s + 1 < NSTEPS) {
            dw_next = dWp[(size_t)(s + 1) * DIM];
            t2 = ts_s[s + 2];
        }

        // broadcast x across the wave via this wave's private LDS row
        xs[wave][lane] = x;
        __builtin_amdgcn_wave_barrier();   // keep compiler from moving reads up

        float ad0 = 0.f, ad1 = 0.f, ac0 = 0.f, ac1 = 0.f;
#pragma unroll
        for (int k4 = 0; k4 < DIM / 4; ++k4) {
            const float4 xv = *(const float4*)(&xs[wave][k4 * 4]);  // broadcast b128
            ad0 = fmaf(Arow[4 * k4 + 0], xv.x, ad0);
            ac0 = fmaf(Crow[4 * k4 + 0], xv.x, ac0);
            ad1 = fmaf(Arow[4 * k4 + 1], xv.y, ad1);
            ac1 = fmaf(Crow[4 * k4 + 1], xv.y, ac1);
            ad0 = fmaf(Arow[4 * k4 + 2], xv.z, ad0);
            ac0 = fmaf(Crow[4 * k4 + 2], xv.z, ac0);
            ad1 = fmaf(Arow[4 * k4 + 3], xv.w, ad1);
            ac1 = fmaf(Crow[4 * k4 + 3], xv.w, ac1);
        }
        __builtin_amdgcn_wave_barrier();   // reads done before next iter's write

        const float dt  = t1 - t0;         // match f32 ts rounding exactly
        const float sdt = sqrtf(dt);
        const float drift_v = (ad0 + ad1) + bj;
        const float diff_v  = (ac0 + ac1) + dj;
        x = fmaf(dt, drift_v, x) + diff_v * (sdt * dw);

        outp[(size_t)(s + 1) * DIM] = x;

        dw = dw_next; t0 = t1; t1 = t2;
    }
}

extern "C" void kernel_launch(void* const* d_in, const int* in_sizes, int n_in,
                              void* d_out, int out_size, void* d_ws, size_t ws_size,
                              hipStream_t stream) {
    const float* x0             = (const float*)d_in[0];
    const float* dW             = (const float*)d_in[1];
    const float* drift          = (const float*)d_in[2];
    const float* drift_bias     = (const float*)d_in[3];
    const float* diffusion      = (const float*)d_in[4];
    const float* diffusion_bias = (const float*)d_in[5];
    const float* ts             = (const float*)d_in[6];
    float* out = (float*)d_out;

    dim3 grid(NPATH / 4);
    dim3 block(256);
    hipLaunchKernelGGL(sde_euler_kernel, grid, block, 0, stream,
                       x0, dW, drift, drift_bias, diffusion, diffusion_bias,
                       ts, out);
}

// Round 3
// 235.904 us; speedup vs baseline: 1.4268x; 1.4268x over previous
//
#include <hip/hip_runtime.h>

#define NPATH  2048
#define DIM    64
#define NSTEPS 500

// One wave (64 lanes) per path. Lane j owns x[j] and holds rows j of the
// drift (A) and diffusion (C) matrices pinned in VGPRs (128 regs).
// Per step: broadcast x through a private LDS row (16 broadcast b128 reads),
// 128 FMAs in 4 chains (round-1-exact association), coalesced dW load
// (4-deep prefetch ring, consume-before-overwrite) + nontemporal ys store.
__global__ __launch_bounds__(256, 2) void sde_euler_kernel(
    const float* __restrict__ x0,
    const float* __restrict__ dW,
    const float* __restrict__ drift,
    const float* __restrict__ drift_bias,
    const float* __restrict__ diffusion,
    const float* __restrict__ diffusion_bias,
    const float* __restrict__ ts,
    float* __restrict__ out)
{
    __shared__ __align__(16) float xs[4][DIM];   // one row per wave in the block
    __shared__ float2 dtp[NSTEPS + 1];           // {dt, sqrt(dt)} per step

    const int wave = threadIdx.x >> 6;
    const int lane = threadIdx.x & 63;
    const int path = (blockIdx.x << 2) + wave;

    // precompute (dt, sqrt(dt)) table in LDS — dt = ts[i+1]-ts[i] in f32,
    // matching the reference's rounding exactly
    for (int i = threadIdx.x; i < NSTEPS; i += 256) {
        const float d = ts[i + 1] - ts[i];
        dtp[i] = make_float2(d, sqrtf(d));
    }
    if (threadIdx.x == 0) dtp[NSTEPS] = make_float2(0.f, 0.f);

    // A row j, C row j -> registers, PINNED so the compiler can't re-load in-loop
    float Arow[DIM], Crow[DIM];
#pragma unroll
    for (int k4 = 0; k4 < DIM / 4; ++k4) {
        const float4 a = *(const float4*)(drift + lane * DIM + k4 * 4);
        const float4 c = *(const float4*)(diffusion + lane * DIM + k4 * 4);
        Arow[4 * k4 + 0] = a.x; Arow[4 * k4 + 1] = a.y;
        Arow[4 * k4 + 2] = a.z; Arow[4 * k4 + 3] = a.w;
        Crow[4 * k4 + 0] = c.x; Crow[4 * k4 + 1] = c.y;
        Crow[4 * k4 + 2] = c.z; Crow[4 * k4 + 3] = c.w;
    }
#pragma unroll
    for (int k = 0; k < DIM; ++k) {
        asm volatile("" : "+v"(Arow[k]), "+v"(Crow[k]));
    }
    const float bj = drift_bias[lane];
    const float dj = diffusion_bias[lane];

    float x = x0[path * DIM + lane];

    const float* dWp  = dW  + (size_t)path * NSTEPS * DIM + lane;
    float*       outp = out + (size_t)path * (NSTEPS + 1) * DIM + lane;
    outp[0] = x;                                 // saved initial state
    xs[wave][lane] = x;                          // broadcast row for step 0

    // 4-deep dW prefetch ring (named regs -> static indexing, no scratch)
    float dw0 = dWp[0];
    float dw1 = dWp[DIM];
    float dw2 = dWp[2 * DIM];
    float dw3 = dWp[3 * DIM];

    __syncthreads();                             // dtp + xs ready

    float dt  = dtp[0].x;
    float sdt = dtp[0].y;

    // NOTE: consume DWCUR into dwc BEFORE the prefetch overwrites the slot
    // (round-2 bug: prefetch clobbered the value 4 steps early).
#define STEP(S, DWCUR, PF)                                              \
    {                                                                   \
        const float dwc = (DWCUR);                                      \
        if (PF) DWCUR##_pf;                                             \
        const float2 dtn = dtp[(S) + 1];                                \
        __builtin_amdgcn_wave_barrier();                                \
        float ad0 = 0.f, ad1 = 0.f, ac0 = 0.f, ac1 = 0.f;               \
        _Pragma("unroll")                                               \
        for (int k4 = 0; k4 < DIM / 4; ++k4) {                          \
            const float4 xv = *(const float4*)(&xs[wave][k4 * 4]);      \
            ad0 = fmaf(Arow[4 * k4 + 0], xv.x, ad0);                    \
            ac0 = fmaf(Crow[4 * k4 + 0], xv.x, ac0);                    \
            ad1 = fmaf(Arow[4 * k4 + 1], xv.y, ad1);                    \
            ac1 = fmaf(Crow[4 * k4 + 1], xv.y, ac1);                    \
            ad0 = fmaf(Arow[4 * k4 + 2], xv.z, ad0);                    \
            ac0 = fmaf(Crow[4 * k4 + 2], xv.z, ac0);                    \
            ad1 = fmaf(Arow[4 * k4 + 3], xv.w, ad1);                    \
            ac1 = fmaf(Crow[4 * k4 + 3], xv.w, ac1);                    \
        }                                                               \
        __builtin_amdgcn_wave_barrier();                                \
        const float drift_v = (ad0 + ad1) + bj;                         \
        const float diff_v  = (ac0 + ac1) + dj;                         \
        x = fmaf(dt, drift_v, x) + diff_v * (sdt * dwc);                \
        __builtin_nontemporal_store(x, &outp[(size_t)((S) + 1) * DIM]); \
        xs[wave][lane] = x;                                             \
        dt = dtn.x; sdt = dtn.y;                                        \
    }

#define dw0_pf dw0 = dWp[(size_t)(s + 4) * DIM]
#define dw1_pf dw1 = dWp[(size_t)(s + 5) * DIM]
#define dw2_pf dw2 = dWp[(size_t)(s + 6) * DIM]
#define dw3_pf dw3 = dWp[(size_t)(s + 7) * DIM]

    // main loop: steps 0..495, prefetching s+4..s+7 (<= 499, in range)
    for (int it = 0; it < (NSTEPS / 4) - 1; ++it) {
        const int s = it * 4;
        STEP(s + 0, dw0, 1)
        STEP(s + 1, dw1, 1)
        STEP(s + 2, dw2, 1)
        STEP(s + 3, dw3, 1)
    }
    // epilogue: steps 496..499, no prefetch
    {
        const int s = NSTEPS - 4;
        STEP(s + 0, dw0, 0)
        STEP(s + 1, dw1, 0)
        STEP(s + 2, dw2, 0)
        STEP(s + 3, dw3, 0)
    }
#undef STEP
#undef dw0_pf
#undef dw1_pf
#undef dw2_pf
#undef dw3_pf
}

extern "C" void kernel_launch(void* const* d_in, const int* in_sizes, int n_in,
                              void* d_out, int out_size, void* d_ws, size_t ws_size,
                              hipStream_t stream) {
    const float* x0             = (const float*)d_in[0];
    const float* dW             = (const float*)d_in[1];
    const float* drift          = (const float*)d_in[2];
    const float* drift_bias     = (const float*)d_in[3];
    const float* diffusion      = (const float*)d_in[4];
    const float* diffusion_bias = (const float*)d_in[5];
    const float* ts             = (const float*)d_in[6];
    float* out = (float*)d_out;

    dim3 grid(NPATH / 4);
    dim3 block(256);
    hipLaunchKernelGGL(sde_euler_kernel, grid, block, 0, stream,
                       x0, dW, drift, drift_bias, diffusion, diffusion_bias,
                       ts, out);
}